// Round 1
// baseline (883.301 us; speedup 1.0000x reference)
//
#include <hip/hip_runtime.h>
#include <stdint.h>

// ---------------------------------------------------------------------------
// Subgraph GNN: out = sum_k MLP_k(hops_k), hops = [X, hop1@X, hop2@X, hop3@X]
// N=8192, IN_DIM=64, H1=128, H2=64, 4 branches.
//
// Strategy: 768 MB of fp32 hop-matrix reads dominate (HBM floor ~122us).
//   k1 prep:      pack X=cat(x,walk) as bf16 in MFMA-B-fragment layout (1 MB)
//   k2 hop_gemm:  Y_m = hop_m @ X via mfma_f32_16x16x32_bf16, A read fp32
//                 direct-to-register (no LDS), cvt to bf16 in-flight.
//   k3 mlp:       fp32 VALU 2-layer MLP over 4 branches, weights in LDS.
// ---------------------------------------------------------------------------

#define N_NODES 8192
#define NDIM 64

typedef __attribute__((ext_vector_type(8))) short short8;   // 8 bf16 (4 VGPRs)
typedef __attribute__((ext_vector_type(4))) float f32x4;    // MFMA C/D

__device__ __forceinline__ unsigned int f2bf(float f) {
  // round-to-nearest-even fp32 -> bf16 bit pattern (data is finite)
  unsigned int u = __builtin_bit_cast(unsigned int, f);
  u += 0x7fffu + ((u >> 16) & 1u);
  return u >> 16;
}

// ---------------------------------------------------------------------------
// prep: Bp[((k>>3)*64 + n)*8 + (k&7)] = X[k][n]  (bf16)
// With s = global thread id, out addr == s  -> fully coalesced stores.
// ---------------------------------------------------------------------------
__global__ void prep_kernel(const float* __restrict__ x,
                            const float* __restrict__ wf,
                            unsigned short* __restrict__ Bp) {
  int s = blockIdx.x * 256 + threadIdx.x;     // 0 .. 524287
  int khi = s >> 9;                           // k / 8
  int rem = s & 511;
  int n   = rem >> 3;
  int klo = rem & 7;
  int k   = (khi << 3) | klo;
  float v = (n < 48) ? x[k * 48 + n] : wf[k * 16 + (n - 48)];
  Bp[s] = (unsigned short)f2bf(v);
}

// ---------------------------------------------------------------------------
// hop_gemm: Y[h] = hop_h @ X   (M=8192, N=64, K=8192)
// grid = 768 blocks (3 hops x 256 m-blocks), 128 threads (2 waves).
// wave: 1 m-tile (16 rows) x 4 n-tiles (64 cols), K-loop step 32.
// A frag: lane holds A[m=lane&15][k0 + (lane>>4)*8 + j], j=0..7 -> 2x float4.
// B frag: one short8 (dwordx4) from packed Bp.
// C/D: col = lane&15, row = (lane>>4)*4 + reg  (m89/m91-verified layout).
// ---------------------------------------------------------------------------
__global__ void hop_gemm(const float* __restrict__ hop1,
                         const float* __restrict__ hop2,
                         const float* __restrict__ hop3,
                         const unsigned short* __restrict__ Bp,
                         float* __restrict__ Y) {
  int bid  = blockIdx.x;
  int h    = bid % 3;
  int mblk = bid / 3;
  const float* A = (h == 0) ? hop1 : (h == 1) ? hop2 : hop3;

  int tid  = threadIdx.x;
  int wave = tid >> 6;
  int lane = tid & 63;
  int n0   = lane & 15;
  int q    = lane >> 4;

  int rowA = mblk * 32 + wave * 16 + n0;
  const float* Arow = A + (size_t)rowA * N_NODES + q * 8;
  const short8* Bp8 = (const short8*)Bp;

  f32x4 acc0 = {0.f, 0.f, 0.f, 0.f};
  f32x4 acc1 = {0.f, 0.f, 0.f, 0.f};
  f32x4 acc2 = {0.f, 0.f, 0.f, 0.f};
  f32x4 acc3 = {0.f, 0.f, 0.f, 0.f};

#pragma unroll 4
  for (int k0 = 0; k0 < N_NODES; k0 += 32) {
    float4 a0 = *(const float4*)(Arow + k0);
    float4 a1 = *(const float4*)(Arow + k0 + 4);
    union { short8 s; unsigned int u[4]; } af;
    af.u[0] = (f2bf(a0.y) << 16) | f2bf(a0.x);
    af.u[1] = (f2bf(a0.w) << 16) | f2bf(a0.z);
    af.u[2] = (f2bf(a1.y) << 16) | f2bf(a1.x);
    af.u[3] = (f2bf(a1.w) << 16) | f2bf(a1.z);

    int bc = ((k0 >> 3) + q) * 64 + n0;      // short8 units
    short8 b0 = Bp8[bc];
    short8 b1 = Bp8[bc + 16];
    short8 b2 = Bp8[bc + 32];
    short8 b3 = Bp8[bc + 48];

    acc0 = __builtin_amdgcn_mfma_f32_16x16x32_bf16(af.s, b0, acc0, 0, 0, 0);
    acc1 = __builtin_amdgcn_mfma_f32_16x16x32_bf16(af.s, b1, acc1, 0, 0, 0);
    acc2 = __builtin_amdgcn_mfma_f32_16x16x32_bf16(af.s, b2, acc2, 0, 0, 0);
    acc3 = __builtin_amdgcn_mfma_f32_16x16x32_bf16(af.s, b3, acc3, 0, 0, 0);
  }

  float* Yo = Y + (size_t)h * (N_NODES * NDIM);
  int rowT = mblk * 32 + wave * 16 + 4 * q;
#pragma unroll
  for (int r = 0; r < 4; ++r) {
    float* yr = Yo + (size_t)(rowT + r) * NDIM + n0;
    yr[0]  = acc0[r];
    yr[16] = acc1[r];
    yr[32] = acc2[r];
    yr[48] = acc3[r];
  }
}

// ---------------------------------------------------------------------------
// mlp: out[row] = sum_k ( relu(Y_k[row] @ W1_k + b1_k) @ W2_k + b2_k )
// 256 blocks x 256 threads, 32 rows/block. fp32 VALU, weights staged in LDS
// (single 32 KB W buffer reused for W1 then W2 to stay under 64 KB static).
// ---------------------------------------------------------------------------
__global__ __launch_bounds__(256) void mlp_kernel(
    const float* __restrict__ x, const float* __restrict__ wf,
    const float* __restrict__ Y,          // [3][8192][64]
    const float* __restrict__ W1, const float* __restrict__ b1,
    const float* __restrict__ W2, const float* __restrict__ b2,
    float* __restrict__ out) {
  __shared__ __attribute__((aligned(16))) float Ys[32 * 64];    //  8 KB
  __shared__ __attribute__((aligned(16))) float Ws[128 * 64];   // 32 KB
  __shared__ __attribute__((aligned(16))) float Hs[32 * 128];   // 16 KB
  __shared__ __attribute__((aligned(16))) float b1s[128];
  __shared__ __attribute__((aligned(16))) float b2s[64];

  int t = threadIdx.x;
  int rowBase = blockIdx.x * 32;

  // layer-1 mapping: 4 rows x 4 feats per thread
  int rg = t >> 5;      // 0..7   -> rows 4*rg .. 4*rg+3
  int fg = t & 31;      // 0..31  -> feats 4*fg .. 4*fg+3
  // layer-2 mapping: 2 rows x 4 cols per thread
  int rg2 = t >> 4;     // 0..15  -> rows 2*rg2, 2*rg2+1
  int cg  = t & 15;     // 0..15  -> cols 4*cg .. 4*cg+3

  float oacc[2][4];
#pragma unroll
  for (int i = 0; i < 2; ++i)
#pragma unroll
    for (int j = 0; j < 4; ++j) oacc[i][j] = 0.f;

  for (int k = 0; k < 4; ++k) {
    // ---- stage branch input rows ----
    for (int i = t; i < 32 * 64; i += 256) {
      float v;
      if (k == 0) {
        int row = rowBase + (i >> 6);
        int n = i & 63;
        v = (n < 48) ? x[row * 48 + n] : wf[row * 16 + (n - 48)];
      } else {
        v = Y[(size_t)(k - 1) * (N_NODES * 64) + (size_t)rowBase * 64 + i];
      }
      Ys[i] = v;
    }
    // ---- stage W1 (64x128), biases ----
    for (int i = t; i < 8192; i += 256) Ws[i] = W1[k * 8192 + i];
    if (t < 128) b1s[t] = b1[k * 128 + t];
    if (t >= 128 && t < 192) b2s[t - 128] = b2[k * 64 + (t - 128)];
    __syncthreads();

    // ---- layer 1: H = relu(Ys @ W1 + b1) ----
    float4 hacc[4];
#pragma unroll
    for (int i = 0; i < 4; ++i) hacc[i] = make_float4(0.f, 0.f, 0.f, 0.f);
    for (int kk = 0; kk < 64; ++kk) {
      float4 wv = *(const float4*)&Ws[kk * 128 + fg * 4];
#pragma unroll
      for (int i = 0; i < 4; ++i) {
        float yv = Ys[(rg * 4 + i) * 64 + kk];   // broadcast within 32 lanes
        hacc[i].x = fmaf(yv, wv.x, hacc[i].x);
        hacc[i].y = fmaf(yv, wv.y, hacc[i].y);
        hacc[i].z = fmaf(yv, wv.z, hacc[i].z);
        hacc[i].w = fmaf(yv, wv.w, hacc[i].w);
      }
    }
    float4 bv = *(const float4*)&b1s[fg * 4];
#pragma unroll
    for (int i = 0; i < 4; ++i) {
      float4 hv;
      hv.x = fmaxf(hacc[i].x + bv.x, 0.f);
      hv.y = fmaxf(hacc[i].y + bv.y, 0.f);
      hv.z = fmaxf(hacc[i].z + bv.z, 0.f);
      hv.w = fmaxf(hacc[i].w + bv.w, 0.f);
      *(float4*)&Hs[(rg * 4 + i) * 128 + fg * 4] = hv;
    }
    __syncthreads();

    // ---- stage W2 (128x64) over the same buffer ----
    for (int i = t; i < 8192; i += 256) Ws[i] = W2[k * 8192 + i];
    __syncthreads();

    // ---- layer 2: out += Hs @ W2 + b2 ----
    float o[2][4];
#pragma unroll
    for (int i = 0; i < 2; ++i) {
      float4 b2v = *(const float4*)&b2s[cg * 4];
      o[i][0] = b2v.x; o[i][1] = b2v.y; o[i][2] = b2v.z; o[i][3] = b2v.w;
    }
    for (int kk = 0; kk < 128; ++kk) {
      float4 wv = *(const float4*)&Ws[kk * 64 + cg * 4];
#pragma unroll
      for (int i = 0; i < 2; ++i) {
        float hv = Hs[(rg2 * 2 + i) * 128 + kk];  // broadcast within 16 lanes
        o[i][0] = fmaf(hv, wv.x, o[i][0]);
        o[i][1] = fmaf(hv, wv.y, o[i][1]);
        o[i][2] = fmaf(hv, wv.z, o[i][2]);
        o[i][3] = fmaf(hv, wv.w, o[i][3]);
      }
    }
#pragma unroll
    for (int i = 0; i < 2; ++i)
#pragma unroll
      for (int j = 0; j < 4; ++j) oacc[i][j] += o[i][j];
    __syncthreads();   // protect Ys/Ws/Hs before next branch restage
  }

#pragma unroll
  for (int i = 0; i < 2; ++i) {
    float4 v;
    v.x = oacc[i][0]; v.y = oacc[i][1]; v.z = oacc[i][2]; v.w = oacc[i][3];
    *(float4*)&out[(size_t)(rowBase + rg2 * 2 + i) * 64 + cg * 4] = v;
  }
}

// ---------------------------------------------------------------------------
extern "C" void kernel_launch(void* const* d_in, const int* in_sizes, int n_in,
                              void* d_out, int out_size, void* d_ws, size_t ws_size,
                              hipStream_t stream) {
  const float* x    = (const float*)d_in[0];
  const float* wf   = (const float*)d_in[1];
  const float* hop1 = (const float*)d_in[2];
  const float* hop2 = (const float*)d_in[3];
  const float* hop3 = (const float*)d_in[4];
  const float* W1   = (const float*)d_in[5];
  const float* b1   = (const float*)d_in[6];
  const float* W2   = (const float*)d_in[7];
  const float* b2   = (const float*)d_in[8];
  float* out = (float*)d_out;

  // workspace layout: [0,1MB) packed bf16 X; [1MB, 1MB+6MB) Y[3][8192][64] f32
  unsigned short* Bp = (unsigned short*)d_ws;
  float* Y = (float*)((char*)d_ws + (1 << 20));

  prep_kernel<<<dim3(524288 / 256), dim3(256), 0, stream>>>(x, wf, Bp);
  hop_gemm<<<dim3(768), dim3(128), 0, stream>>>(hop1, hop2, hop3, Bp, Y);
  mlp_kernel<<<dim3(256), dim3(256), 0, stream>>>(x, wf, Y, W1, b1, W2, b2, out);
}

// Round 2
// 808.233 us; speedup vs baseline: 1.0929x; 1.0929x over previous
//
#include <hip/hip_runtime.h>
#include <stdint.h>

// ---------------------------------------------------------------------------
// Subgraph GNN: out = sum_k MLP_k(hops_k), hops = [X, hop1@X, hop2@X, hop3@X]
// N=8192, IN_DIM=64, H1=128, H2=64, 4 branches.
//
// R2 changes vs R1 (hop_gemm was latency-bound: VGPR=32, 17% occupancy,
// 1.08 TB/s):
//   - hop_gemm: K-split x4 within a 256-thread block (wave w owns K-chunk
//     w*2048..), 1536 blocks -> 24 waves/CU; explicit 2-deep register
//     double-buffer for A (HBM) and B (L2) so loads stay in flight; partial
//     accs reduced across the 4 waves through a 16 KB LDS tile (no atomics).
//   - mlp: 512 blocks x 16 rows (was 256 x 32 at 1 block/CU); W1/W2 read
//     directly from global (L1/L2-resident), LDS only for Ys/Hs with +pad
//     to break 4-way broadcast bank conflicts.
// ---------------------------------------------------------------------------

#define N_NODES 8192
#define NDIM 64

typedef __attribute__((ext_vector_type(8))) short short8;   // 8 bf16 (4 VGPRs)
typedef __attribute__((ext_vector_type(4))) float f32x4;    // MFMA C/D

__device__ __forceinline__ unsigned int f2bf(float f) {
  // round-to-nearest-even fp32 -> bf16 bit pattern (data is finite)
  unsigned int u = __builtin_bit_cast(unsigned int, f);
  u += 0x7fffu + ((u >> 16) & 1u);
  return u >> 16;
}

// ---------------------------------------------------------------------------
// prep: Bp[((k>>3)*64 + n)*8 + (k&7)] = X[k][n]  (bf16), X = cat(x, wf)
// s = global thread id == output address -> coalesced stores; reads L1-cached.
// ---------------------------------------------------------------------------
__global__ void prep_kernel(const float* __restrict__ x,
                            const float* __restrict__ wf,
                            unsigned short* __restrict__ Bp) {
  int s = blockIdx.x * 256 + threadIdx.x;     // 0 .. 524287
  int khi = s >> 9;                           // k / 8
  int rem = s & 511;
  int n   = rem >> 3;
  int klo = rem & 7;
  int k   = (khi << 3) | klo;
  float v = (n < 48) ? x[k * 48 + n] : wf[k * 16 + (n - 48)];
  Bp[s] = (unsigned short)f2bf(v);
}

// ---------------------------------------------------------------------------
// hop_gemm: Y[h] = hop_h @ X   (M=8192, N=64, K=8192)
// grid = 1536 blocks (3 hops x 512 m-tiles of 16 rows), 256 threads (4 waves).
// wave w computes the partial over K-chunk [w*2048, (w+1)*2048); the 4
// partial 16x64 tiles are summed through LDS and stored once.
// A frag: lane holds A[m=lane&15][kc + (lane>>4)*8 + j], j=0..7 -> 2x float4.
// B frag: one short8 (dwordx4) from packed Bp.
// C/D: col = lane&15, row = (lane>>4)*4 + reg  (m89/m91-verified layout).
// ---------------------------------------------------------------------------
__global__ __launch_bounds__(256, 6) void hop_gemm(
    const float* __restrict__ hop1,
    const float* __restrict__ hop2,
    const float* __restrict__ hop3,
    const unsigned short* __restrict__ Bp,
    float* __restrict__ Y) {
  __shared__ __attribute__((aligned(16))) float red[4 * 1024];  // 16 KB

  int bid  = blockIdx.x;
  int h    = bid % 3;
  int mblk = bid / 3;
  const float* A = (h == 0) ? hop1 : (h == 1) ? hop2 : hop3;

  int tid  = threadIdx.x;
  int w    = tid >> 6;          // wave id = K-split id
  int lane = tid & 63;
  int n0   = lane & 15;
  int q    = lane >> 4;

  int rowA = mblk * 16 + n0;
  const float* Arow = A + (size_t)rowA * N_NODES + w * 2048 + q * 8;
  const short8* Bw  = (const short8*)Bp + ((size_t)(w * 256 + q)) * 64 + n0;

  f32x4 acc0 = {0.f, 0.f, 0.f, 0.f};
  f32x4 acc1 = {0.f, 0.f, 0.f, 0.f};
  f32x4 acc2 = {0.f, 0.f, 0.f, 0.f};
  f32x4 acc3 = {0.f, 0.f, 0.f, 0.f};

  float4 xa0, xa1, ya0, ya1;            // A double-buffer
  short8 xb0, xb1, xb2, xb3;            // B double-buffer
  short8 yb0, yb1, yb2, yb3;

#define LOAD_A(s, A0, A1)                                \
  do {                                                   \
    const float* _p = Arow + 32 * (s);                   \
    A0 = *(const float4*)_p;                             \
    A1 = *(const float4*)(_p + 4);                       \
  } while (0)

#define LOAD_B(s, B0, B1, B2, B3)                        \
  do {                                                   \
    const short8* _p = Bw + 256 * (s);                   \
    B0 = _p[0]; B1 = _p[16]; B2 = _p[32]; B3 = _p[48];   \
  } while (0)

#define PROC(A0, A1, B0, B1, B2, B3)                                        \
  do {                                                                      \
    union { short8 s; unsigned int u[4]; } af;                              \
    af.u[0] = (f2bf((A0).y) << 16) | f2bf((A0).x);                          \
    af.u[1] = (f2bf((A0).w) << 16) | f2bf((A0).z);                          \
    af.u[2] = (f2bf((A1).y) << 16) | f2bf((A1).x);                          \
    af.u[3] = (f2bf((A1).w) << 16) | f2bf((A1).z);                          \
    acc0 = __builtin_amdgcn_mfma_f32_16x16x32_bf16(af.s, B0, acc0, 0, 0, 0);\
    acc1 = __builtin_amdgcn_mfma_f32_16x16x32_bf16(af.s, B1, acc1, 0, 0, 0);\
    acc2 = __builtin_amdgcn_mfma_f32_16x16x32_bf16(af.s, B2, acc2, 0, 0, 0);\
    acc3 = __builtin_amdgcn_mfma_f32_16x16x32_bf16(af.s, B3, acc3, 0, 0, 0);\
  } while (0)

  // 64 k-steps per wave, software-pipelined 2-deep (x buf / y buf).
  LOAD_A(0, xa0, xa1);
  LOAD_B(0, xb0, xb1, xb2, xb3);
#pragma unroll 1
  for (int s = 0; s < 62; s += 2) {
    LOAD_A(s + 1, ya0, ya1);
    LOAD_B(s + 1, yb0, yb1, yb2, yb3);
    PROC(xa0, xa1, xb0, xb1, xb2, xb3);
    LOAD_A(s + 2, xa0, xa1);
    LOAD_B(s + 2, xb0, xb1, xb2, xb3);
    PROC(ya0, ya1, yb0, yb1, yb2, yb3);
  }
  LOAD_A(63, ya0, ya1);
  LOAD_B(63, yb0, yb1, yb2, yb3);
  PROC(xa0, xa1, xb0, xb1, xb2, xb3);
  PROC(ya0, ya1, yb0, yb1, yb2, yb3);

#undef LOAD_A
#undef LOAD_B
#undef PROC

  // ---- cross-wave K reduction through LDS ----
  {
    float* rw = &red[w * 1024 + lane * 4];
    *(f32x4*)(rw)       = acc0;   // nt=0 at +0
    *(f32x4*)(rw + 256) = acc1;   // nt=1
    *(f32x4*)(rw + 512) = acc2;   // nt=2
    *(f32x4*)(rw + 768) = acc3;   // nt=3
  }
  __syncthreads();

  {
    int t = tid;                      // 0..255 = nt(2b) | lane(6b)
    f32x4 v = *(const f32x4*)&red[t * 4];
    v += *(const f32x4*)&red[1024 + t * 4];
    v += *(const f32x4*)&red[2048 + t * 4];
    v += *(const f32x4*)&red[3072 + t * 4];

    int nt    = t >> 6;
    int lane2 = t & 63;
    int q2    = lane2 >> 4;
    int n02   = lane2 & 15;
    int col   = nt * 16 + n02;
    float* Yo = Y + (size_t)h * (N_NODES * NDIM)
                  + (size_t)(mblk * 16 + q2 * 4) * NDIM + col;
    Yo[0 * NDIM] = v.x;
    Yo[1 * NDIM] = v.y;
    Yo[2 * NDIM] = v.z;
    Yo[3 * NDIM] = v.w;
  }
}

// ---------------------------------------------------------------------------
// mlp: out[row] = sum_k ( relu(Y_k[row] @ W1_k + b1_k) @ W2_k + b2_k )
// 512 blocks x 256 threads, 16 rows/block. fp32 VALU. Weights read straight
// from global (every block reads the same 256 KB -> L1/L2 resident).
// LDS only for activations; rows padded (68 / 132) so the per-row broadcast
// reads land in distinct banks across the 4 row-groups of a wave.
// ---------------------------------------------------------------------------
#define YS_LD 68
#define HS_LD 132
__global__ __launch_bounds__(256) void mlp_kernel(
    const float* __restrict__ x, const float* __restrict__ wf,
    const float* __restrict__ Y,          // [3][8192][64]
    const float* __restrict__ W1, const float* __restrict__ b1,
    const float* __restrict__ W2, const float* __restrict__ b2,
    float* __restrict__ out) {
  __shared__ __attribute__((aligned(16))) float Ys[16 * YS_LD];   // 4.25 KB
  __shared__ __attribute__((aligned(16))) float Hs[16 * HS_LD];   // 8.25 KB
  __shared__ float b1s[128];
  __shared__ float b2s[64];

  int t = threadIdx.x;
  int rowBase = blockIdx.x * 16;

  int r  = t >> 4;           // 0..15: row (both layers)
  int c8 = (t & 15) * 8;     // layer-1 cols
  int c4 = (t & 15) * 4;     // layer-2 cols

  float oacc[4] = {0.f, 0.f, 0.f, 0.f};

  for (int k = 0; k < 4; ++k) {
    // ---- stage activations + biases ----
    for (int i = t; i < 16 * 64; i += 256) {
      int row = i >> 6;
      int n   = i & 63;
      float v;
      if (k == 0) {
        int grow = rowBase + row;
        v = (n < 48) ? x[grow * 48 + n] : wf[grow * 16 + (n - 48)];
      } else {
        v = Y[(size_t)(k - 1) * (N_NODES * 64) + (size_t)(rowBase + row) * 64 + n];
      }
      Ys[row * YS_LD + n] = v;
    }
    if (t < 128) b1s[t] = b1[k * 128 + t];
    else if (t < 192) b2s[t - 128] = b2[k * 64 + (t - 128)];
    __syncthreads();

    // ---- layer 1: H = relu(Ys @ W1 + b1), thread = 1 row x 8 cols ----
    const float* W1k = W1 + k * 8192;
    float f0 = 0.f, f1 = 0.f, f2 = 0.f, f3 = 0.f;
    float f4 = 0.f, f5 = 0.f, f6 = 0.f, f7 = 0.f;
#pragma unroll 4
    for (int kk = 0; kk < 64; ++kk) {
      float yv = Ys[r * YS_LD + kk];
      float4 w0 = *(const float4*)&W1k[kk * 128 + c8];
      float4 w1 = *(const float4*)&W1k[kk * 128 + c8 + 4];
      f0 = fmaf(yv, w0.x, f0); f1 = fmaf(yv, w0.y, f1);
      f2 = fmaf(yv, w0.z, f2); f3 = fmaf(yv, w0.w, f3);
      f4 = fmaf(yv, w1.x, f4); f5 = fmaf(yv, w1.y, f5);
      f6 = fmaf(yv, w1.z, f6); f7 = fmaf(yv, w1.w, f7);
    }
    {
      float4 ba = *(const float4*)&b1s[c8];
      float4 bb = *(const float4*)&b1s[c8 + 4];
      float4 h0, h1;
      h0.x = fmaxf(f0 + ba.x, 0.f); h0.y = fmaxf(f1 + ba.y, 0.f);
      h0.z = fmaxf(f2 + ba.z, 0.f); h0.w = fmaxf(f3 + ba.w, 0.f);
      h1.x = fmaxf(f4 + bb.x, 0.f); h1.y = fmaxf(f5 + bb.y, 0.f);
      h1.z = fmaxf(f6 + bb.z, 0.f); h1.w = fmaxf(f7 + bb.w, 0.f);
      *(float4*)&Hs[r * HS_LD + c8]     = h0;
      *(float4*)&Hs[r * HS_LD + c8 + 4] = h1;
    }
    __syncthreads();

    // ---- layer 2: out += Hs @ W2 + b2, thread = 1 row x 4 cols ----
    const float* W2k = W2 + k * 8192;
    float o0 = b2s[c4], o1 = b2s[c4 + 1], o2 = b2s[c4 + 2], o3 = b2s[c4 + 3];
#pragma unroll 4
    for (int kk = 0; kk < 128; ++kk) {
      float hv = Hs[r * HS_LD + kk];
      float4 wv = *(const float4*)&W2k[kk * 64 + c4];
      o0 = fmaf(hv, wv.x, o0); o1 = fmaf(hv, wv.y, o1);
      o2 = fmaf(hv, wv.z, o2); o3 = fmaf(hv, wv.w, o3);
    }
    oacc[0] += o0; oacc[1] += o1; oacc[2] += o2; oacc[3] += o3;
    __syncthreads();   // protect Ys/Hs before next branch restage
  }

  float4 v;
  v.x = oacc[0]; v.y = oacc[1]; v.z = oacc[2]; v.w = oacc[3];
  *(float4*)&out[(size_t)(rowBase + r) * 64 + c4] = v;
}

// ---------------------------------------------------------------------------
extern "C" void kernel_launch(void* const* d_in, const int* in_sizes, int n_in,
                              void* d_out, int out_size, void* d_ws, size_t ws_size,
                              hipStream_t stream) {
  const float* x    = (const float*)d_in[0];
  const float* wf   = (const float*)d_in[1];
  const float* hop1 = (const float*)d_in[2];
  const float* hop2 = (const float*)d_in[3];
  const float* hop3 = (const float*)d_in[4];
  const float* W1   = (const float*)d_in[5];
  const float* b1   = (const float*)d_in[6];
  const float* W2   = (const float*)d_in[7];
  const float* b2   = (const float*)d_in[8];
  float* out = (float*)d_out;

  // workspace layout: [0,1MB) packed bf16 X; [1MB, 1MB+6MB) Y[3][8192][64] f32
  unsigned short* Bp = (unsigned short*)d_ws;
  float* Y = (float*)((char*)d_ws + (1 << 20));

  prep_kernel<<<dim3(524288 / 256), dim3(256), 0, stream>>>(x, wf, Bp);
  hop_gemm<<<dim3(1536), dim3(256), 0, stream>>>(hop1, hop2, hop3, Bp, Y);
  mlp_kernel<<<dim3(512), dim3(256), 0, stream>>>(x, wf, Y, W1, b1, W2, b2, out);
}